// Round 4
// baseline (373.328 us; speedup 1.0000x reference)
//
#include <hip/hip_runtime.h>
#include <hip/hip_bf16.h>
#include <stdint.h>

// Problem constants (fixed by setup_inputs)
#define Bn 64
#define Sn 2048
#define Dn 768
#define An 256
#define EPSF 1e-7f
#define ROWS 32               // s-rows per chunk
#define NCHUNK (Sn / ROWS)    // 64 chunks per batch
#define NK (Dn / 32)          // 24 K-steps of 32
#define CPB 16                // chunks per block
#define NBLK ((Bn * NCHUNK) / CPB)   // 256 blocks == 1 per CU

typedef __bf16 bf16x8 __attribute__((ext_vector_type(8)));
typedef float f32x4 __attribute__((ext_vector_type(4)));

// ---------------- pack W (fp32 row-major DxA) -> bf16 MFMA-B-fragment layout ----
__global__ void pack_w_kernel(const float* __restrict__ W, unsigned short* __restrict__ pw) {
  int kk = blockIdx.x >> 4;     // 0..23
  int cb = blockIdx.x & 15;     // 0..15
  int l  = threadIdx.x;         // 0..63
  int a  = cb * 16 + (l & 15);
  int k0 = kk * 32 + (l >> 4) * 8;
  bf16x8 pk;
#pragma unroll
  for (int j = 0; j < 8; ++j) pk[j] = (__bf16)W[(k0 + j) * An + a];
  *(bf16x8*)(pw + ((size_t)((kk * 16 + cb) * 64 + l)) * 8) = pk;
}

// ---------------- main fused kernel: producer/consumer, fixed pipeline ----------------
// 512 threads = 8 waves, 1 block/CU (LDS ~105KB), 2 waves/SIMD (VGPR cap 256).
// Waves 0-3: consumers (MFMA K-loop from LDS x + L2-hot W, epilogue, pooling).
// Waves 4-7: producers (global fp32 -> regs [in flight across barriers] -> bf16 LDS).
// Raw s_barrier everywhere; vmcnt is NEVER drained at barriers -> HBM streams
// continuously. Producer issues chunk i+2 loads AFTER consuming chunk i+1 regs
// (one-iteration prefetch depth), pinned by a compiler memory barrier.
__launch_bounds__(512, 2)
__global__ void attn_pool_main(const float* __restrict__ x,
                               const unsigned short* __restrict__ pw,
                               const float* __restrict__ bias,
                               const float* __restrict__ u,
                               const int* __restrict__ mask,
                               float* __restrict__ outpart,
                               float* __restrict__ sumpart) {
  __shared__ __align__(16) char xs[2][49152];   // 32 rows x 768 bf16, XOR-swizzled
  __shared__ float aitp[128];
  __shared__ float aitv[32];
  __shared__ float outred[1536];

  const int tid  = threadIdx.x;
  const int lane = tid & 63;
  const int wv   = tid >> 6;        // 0..7
  const bool prod = (wv >= 4);
  const int w    = wv & 3;          // consumer colblock

  const int cid0 = blockIdx.x * CPB;
  const int b    = cid0 >> 6;       // batch (constant across the block's 16 chunks)

  // ---- prologue: all 8 waves stage chunk cid0 into xs[0] ----
  {
    const int s0 = (cid0 & 63) * ROWS;
    const float* xb = x + ((size_t)b * Sn + s0) * Dn;
#pragma unroll
    for (int j = 0; j < 6; ++j) {
      int unit = tid + j * 512;          // 0..3071
      int row = unit / 96, ku = unit % 96;
      const float4* g = (const float4*)(xb + row * Dn + ku * 8);
      float4 v0 = g[0], v1 = g[1];
      bf16x8 pk;
      pk[0] = (__bf16)v0.x; pk[1] = (__bf16)v0.y; pk[2] = (__bf16)v0.z; pk[3] = (__bf16)v0.w;
      pk[4] = (__bf16)v1.x; pk[5] = (__bf16)v1.y; pk[6] = (__bf16)v1.z; pk[7] = (__bf16)v1.w;
      int off = (row * 1536 + ku * 16) ^ ((row & 7) << 4);
      *(bf16x8*)(xs[0] + off) = pk;
    }
  }
  __syncthreads();   // one full drain at start is fine

  const int arow  = lane & 15;
  const int akoff = (lane >> 4) * 16;
  const int swz   = (arow & 7) << 4;
  const char* wlane = (const char*)pw + (size_t)(w * 4) * 1024 + (size_t)lane * 16;
  const int ptid = tid - 256;

  float4 ld0[12], ld1[12];

  if (prod) {
    // issue chunk cid0+1 loads (consumed at iteration 0's cvt phase)
    const int nc = cid0 + 1;
    const float* xb = x + ((size_t)b * Sn + (size_t)(nc & 63) * ROWS) * Dn;
#pragma unroll
    for (int j = 0; j < 12; ++j) {
      int unit = ptid + j * 256;
      int row = unit / 96, ku = unit % 96;
      const float4* g = (const float4*)(xb + row * Dn + ku * 8);
      ld0[j] = g[0];
      ld1[j] = g[1];
    }
    asm volatile("" ::: "memory");   // pin load issue here (no sinking)
  }

  for (int i = 0; i < CPB; ++i) {
    const int cid = cid0 + i;
    const int s0  = (cid & 63) * ROWS;
    const char* cbuf = xs[i & 1];

    if (prod) {
      // ---- cvt + write chunk i+1 (vmcnt waits only on OUR loads, issued
      //      one iteration ago -> already landed), then issue chunk i+2 ----
      if (i + 1 < CPB) {
        char* nbuf = xs[(i + 1) & 1];
#pragma unroll
        for (int j = 0; j < 12; ++j) {
          int unit = ptid + j * 256;
          int row = unit / 96, ku = unit % 96;
          bf16x8 pk;
          pk[0] = (__bf16)ld0[j].x; pk[1] = (__bf16)ld0[j].y;
          pk[2] = (__bf16)ld0[j].z; pk[3] = (__bf16)ld0[j].w;
          pk[4] = (__bf16)ld1[j].x; pk[5] = (__bf16)ld1[j].y;
          pk[6] = (__bf16)ld1[j].z; pk[7] = (__bf16)ld1[j].w;
          int off = (row * 1536 + ku * 16) ^ ((row & 7) << 4);
          *(bf16x8*)(nbuf + off) = pk;
        }
        asm volatile("s_waitcnt lgkmcnt(0)" ::: "memory");  // publish before S1
        if (i + 2 < CPB) {
          const int nc = cid + 2;
          const float* xb = x + ((size_t)b * Sn + (size_t)(nc & 63) * ROWS) * Dn;
#pragma unroll
          for (int j = 0; j < 12; ++j) {
            int unit = ptid + j * 256;
            int row = unit / 96, ku = unit % 96;
            const float4* g = (const float4*)(xb + row * Dn + ku * 8);
            ld0[j] = g[0];
            ld1[j] = g[1];
          }
          asm volatile("" ::: "memory");   // pin issue before the barriers
        }
      }
      __builtin_amdgcn_s_barrier();   // S1
      __builtin_amdgcn_s_barrier();   // S2
      __builtin_amdgcn_s_barrier();   // S3
    } else {
      // ---- consumer: K-loop over current chunk ----
      float mval = 0.f;
      if (tid < 32) mval = (float)mask[(size_t)b * Sn + s0 + tid];

      f32x4 acc[2][4];
#pragma unroll
      for (int p = 0; p < 2; ++p)
#pragma unroll
        for (int q = 0; q < 4; ++q) acc[p][q] = (f32x4){0.f, 0.f, 0.f, 0.f};

#pragma unroll 4
      for (int kk = 0; kk < NK; ++kk) {
        const char* wk = wlane + (size_t)kk * 16384;
        bf16x8 bfr0 = *(const bf16x8*)(wk);
        bf16x8 bfr1 = *(const bf16x8*)(wk + 1024);
        bf16x8 bfr2 = *(const bf16x8*)(wk + 2048);
        bf16x8 bfr3 = *(const bf16x8*)(wk + 3072);
        bf16x8 a0 = *(const bf16x8*)(cbuf + (((arow     ) * 1536 + kk * 64 + akoff) ^ swz));
        bf16x8 a1 = *(const bf16x8*)(cbuf + (((arow + 16) * 1536 + kk * 64 + akoff) ^ swz));
        acc[0][0] = __builtin_amdgcn_mfma_f32_16x16x32_bf16(a0, bfr0, acc[0][0], 0, 0, 0);
        acc[1][0] = __builtin_amdgcn_mfma_f32_16x16x32_bf16(a1, bfr0, acc[1][0], 0, 0, 0);
        acc[0][1] = __builtin_amdgcn_mfma_f32_16x16x32_bf16(a0, bfr1, acc[0][1], 0, 0, 0);
        acc[1][1] = __builtin_amdgcn_mfma_f32_16x16x32_bf16(a1, bfr1, acc[1][1], 0, 0, 0);
        acc[0][2] = __builtin_amdgcn_mfma_f32_16x16x32_bf16(a0, bfr2, acc[0][2], 0, 0, 0);
        acc[1][2] = __builtin_amdgcn_mfma_f32_16x16x32_bf16(a1, bfr2, acc[1][2], 0, 0, 0);
        acc[0][3] = __builtin_amdgcn_mfma_f32_16x16x32_bf16(a0, bfr3, acc[0][3], 0, 0, 0);
        acc[1][3] = __builtin_amdgcn_mfma_f32_16x16x32_bf16(a1, bfr3, acc[1][3], 0, 0, 0);
      }

      // ---- epilogue: tanh + dot with u -> per-row partials into aitp ----
      float rowp[8];
#pragma unroll
      for (int p = 0; p < 8; ++p) rowp[p] = 0.f;
#pragma unroll
      for (int cbi = 0; cbi < 4; ++cbi) {
        int col = w * 64 + cbi * 16 + (lane & 15);
        float bia = bias[col];
        float uv  = u[col];
#pragma unroll
        for (int rb = 0; rb < 2; ++rb) {
#pragma unroll
          for (int r = 0; r < 4; ++r) {
            float v = acc[rb][cbi][r] + bia;
            v = fminf(fmaxf(v, -15.f), 15.f);
            float e2 = __expf(2.f * v);
            float th = (e2 - 1.f) * __builtin_amdgcn_rcpf(e2 + 1.f);
            rowp[rb * 4 + r] += th * uv;
          }
        }
      }
#pragma unroll
      for (int m = 1; m < 16; m <<= 1)
#pragma unroll
        for (int p = 0; p < 8; ++p) rowp[p] += __shfl_xor(rowp[p], m, 64);

      if ((lane & 15) == 0) {
        int rbase = (lane >> 4) * 4;
#pragma unroll
        for (int rb = 0; rb < 2; ++rb)
#pragma unroll
          for (int r = 0; r < 4; ++r)
            aitp[w * 32 + rb * 16 + rbase + r] = rowp[rb * 4 + r];
      }
      asm volatile("s_waitcnt lgkmcnt(0)" ::: "memory");
      __builtin_amdgcn_s_barrier();   // S1: aitp ready; next x-buffer published

      if (tid < 32) {
        float s = aitp[tid] + aitp[32 + tid] + aitp[64 + tid] + aitp[96 + tid];
        float av = __expf(s) * mval;
        aitv[tid] = av;
        float t = av;
#pragma unroll
        for (int m = 1; m < 32; m <<= 1) t += __shfl_xor(t, m, 64);
        if (tid == 0) sumpart[cid] = t;
      }
      asm volatile("s_waitcnt lgkmcnt(0)" ::: "memory");
      __builtin_amdgcn_s_barrier();   // S2: aitv ready

      if (tid < 192) {
        int rg = tid / 96;
        int du = tid % 96;
        float pac[8];
#pragma unroll
        for (int e = 0; e < 8; ++e) pac[e] = 0.f;
#pragma unroll
        for (int rr = 0; rr < 16; ++rr) {
          int row = rg * 16 + rr;
          int off = (row * 1536 + du * 16) ^ ((row & 7) << 4);
          bf16x8 xv = *(const bf16x8*)(cbuf + off);
          float a = aitv[row];
#pragma unroll
          for (int e = 0; e < 8; ++e) pac[e] += a * (float)xv[e];
        }
#pragma unroll
        for (int e = 0; e < 8; ++e) outred[rg * 768 + du * 8 + e] = pac[e];
      }
      asm volatile("s_waitcnt lgkmcnt(0)" ::: "memory");
      __builtin_amdgcn_s_barrier();   // S3: outred ready; cbuf reads done

      {
        float* op = outpart + (size_t)cid * Dn;
#pragma unroll
        for (int j = 0; j < 2; ++j) {
          int d = tid + j * 256;
          op[d] = outred[d] + outred[768 + d];
        }
        int d2 = tid + 512;
        op[d2] = outred[d2] + outred[768 + d2];
      }
    }
  }
}

// ---------------- finalize: out[b,d] = sum_c outpart / (sum_c sumpart + eps) ----
// grid = 64 b x 3 slabs of 256 d
__global__ void finalize_kernel(const float* __restrict__ outpart,
                                const float* __restrict__ sumpart,
                                float* __restrict__ out) {
  __shared__ float sh;
  int b = blockIdx.x / 3, slab = blockIdx.x % 3;
  int tid = threadIdx.x;
  if (tid < 64) {
    float v = sumpart[b * 64 + tid];
#pragma unroll
    for (int m = 1; m < 64; m <<= 1) v += __shfl_xor(v, m, 64);
    if (tid == 0) sh = v + EPSF;
  }
  __syncthreads();
  float inv = 1.0f / sh;
  int d = slab * 256 + tid;
  const float* p = outpart + (size_t)b * 64 * Dn + d;
  float s = 0.f;
#pragma unroll 8
  for (int c = 0; c < 64; ++c) s += p[(size_t)c * Dn];
  out[b * Dn + d] = s * inv;
}

extern "C" void kernel_launch(void* const* d_in, const int* in_sizes, int n_in,
                              void* d_out, int out_size, void* d_ws, size_t ws_size,
                              hipStream_t stream) {
  const float* x    = (const float*)d_in[0];
  const float* W    = (const float*)d_in[1];
  const float* bias = (const float*)d_in[2];
  const float* u    = (const float*)d_in[3];
  const int*   mask = (const int*)d_in[4];
  float* out = (float*)d_out;

  unsigned short* pw = (unsigned short*)d_ws;                      // 393216 B
  float* outpart = (float*)((char*)d_ws + 393216);                 // 64*64*768*4 = 12.58 MB
  float* sumpart = (float*)((char*)d_ws + 393216 + 12582912);      // 16 KB

  hipLaunchKernelGGL(pack_w_kernel, dim3(24 * 16), dim3(64), 0, stream, W, pw);
  hipLaunchKernelGGL(attn_pool_main, dim3(NBLK), dim3(512), 0, stream,
                     x, pw, bias, u, mask, outpart, sumpart);
  hipLaunchKernelGGL(finalize_kernel, dim3(Bn * 3), dim3(256), 0, stream,
                     outpart, sumpart, out);
}

// Round 5
// 155.556 us; speedup vs baseline: 2.4000x; 2.4000x over previous
//
#include <hip/hip_runtime.h>
#include <hip/hip_bf16.h>
#include <stdint.h>

// Problem constants (fixed by setup_inputs)
#define Bn 64
#define Sn 2048
#define Dn 768
#define An 256
#define EPSF 1e-7f
#define ROWS 32               // s-rows per chunk
#define NCHUNK (Sn / ROWS)    // 64 chunks per batch
#define NK (Dn / 32)          // 24 K-steps of 32
#define CPB 16                // chunks per block
#define NBLK ((Bn * NCHUNK) / CPB)   // 256 blocks == 1 per CU

typedef __bf16 bf16x8 __attribute__((ext_vector_type(8)));
typedef float f32x4 __attribute__((ext_vector_type(4)));

// ---------------- pack W (fp32 row-major DxA) -> bf16 MFMA-B-fragment layout ----
// packed[( (kk*16 + cb)*64 + lane )*8 + e] = bf16( W[kk*32 + (lane>>4)*8 + e][cb*16 + (lane&15)] )
__global__ void pack_w_kernel(const float* __restrict__ W, unsigned short* __restrict__ pw) {
  int kk = blockIdx.x >> 4;     // 0..23
  int cb = blockIdx.x & 15;     // 0..15
  int l  = threadIdx.x;         // 0..63
  int a  = cb * 16 + (l & 15);
  int k0 = kk * 32 + (l >> 4) * 8;
  bf16x8 pk;
#pragma unroll
  for (int j = 0; j < 8; ++j) pk[j] = (__bf16)W[(k0 + j) * An + a];
  *(bf16x8*)(pw + ((size_t)((kk * 16 + cb) * 64 + l)) * 8) = pk;
}

// ---------------- main fused kernel: persistent homogeneous pipeline ----------------
// 256 blocks (1/CU), 512 threads = 8 waves (2/SIMD), CPB=16 chunks each.
// All waves: stage-prefetch (global fp32 -> 12 float4 regs, one chunk ahead),
// MFMA K-loop (x from LDS bf16, W B-frags from L2), epilogue, pooling.
// Raw s_barrier + lgkm-only drains: vmcnt NEVER drained at barriers, so the
// HBM stream runs continuously. Issue of chunk i+2 happens right after the
// cvt phase frees the registers -> HBM gap per iteration = cvt time only.
__launch_bounds__(512, 2)
__global__ void attn_pool_main(const float* __restrict__ x,
                               const unsigned short* __restrict__ pw,
                               const float* __restrict__ bias,
                               const float* __restrict__ u,
                               const int* __restrict__ mask,
                               float* __restrict__ outpart,
                               float* __restrict__ sumpart) {
  __shared__ __align__(16) char xs[2][49152];   // 2 x (32 rows x 768 bf16), XOR-swizzled
  __shared__ float aitp[256];                   // [8 waves][32 rows] u-dot partials
  __shared__ float aitv[32];
  __shared__ float outred[3072];                // [4 row-groups][768]

  const int tid  = threadIdx.x;
  const int lane = tid & 63;
  const int wv   = tid >> 6;        // 0..7

  const int cid0 = blockIdx.x * CPB;
  const int b    = cid0 >> 6;       // constant per block (64 % CPB == 0)

  const int arow  = lane & 15;
  const int akoff = (lane >> 4) * 16;
  const int swz   = (arow & 7) << 4;
  const char* wlane = (const char*)pw + (size_t)(wv * 2) * 1024 + (size_t)lane * 16;

  float4 ld0[6], ld1[6];

  // ---- prologue: stage chunk cid0 synchronously into xs[0] ----
  {
    const float* xb = x + ((size_t)b * Sn + (size_t)(cid0 & 63) * ROWS) * Dn;
#pragma unroll
    for (int j = 0; j < 6; ++j) {
      int unit = tid + j * 512;          // 0..3071, 8 k-elems each
      int row = unit / 96, ku = unit % 96;
      const float4* g = (const float4*)(xb + row * Dn + ku * 8);
      ld0[j] = g[0];
      ld1[j] = g[1];
    }
#pragma unroll
    for (int j = 0; j < 6; ++j) {
      int unit = tid + j * 512;
      int row = unit / 96, ku = unit % 96;
      bf16x8 pk;
      pk[0] = (__bf16)ld0[j].x; pk[1] = (__bf16)ld0[j].y;
      pk[2] = (__bf16)ld0[j].z; pk[3] = (__bf16)ld0[j].w;
      pk[4] = (__bf16)ld1[j].x; pk[5] = (__bf16)ld1[j].y;
      pk[6] = (__bf16)ld1[j].z; pk[7] = (__bf16)ld1[j].w;
      int off = (row * 1536 + ku * 16) ^ ((row & 7) << 4);
      *(bf16x8*)(xs[0] + off) = pk;
    }
  }
  // ---- issue chunk cid0+1 loads (stay in flight across barriers) ----
  {
    const int nc = cid0 + 1;
    const float* xb = x + ((size_t)b * Sn + (size_t)(nc & 63) * ROWS) * Dn;
#pragma unroll
    for (int j = 0; j < 6; ++j) {
      int unit = tid + j * 512;
      int row = unit / 96, ku = unit % 96;
      const float4* g = (const float4*)(xb + row * Dn + ku * 8);
      ld0[j] = g[0];
      ld1[j] = g[1];
    }
    asm volatile("" ::: "memory");   // pin load issue here
  }
  asm volatile("s_waitcnt lgkmcnt(0)" ::: "memory");
  __builtin_amdgcn_s_barrier();      // xs[0] published; chunk-1 loads streaming

  for (int i = 0; i < CPB; ++i) {
    const int cid = cid0 + i;
    const int s0  = (cid & 63) * ROWS;
    const char* cbuf = xs[i & 1];

    float mval = 0.f;
    if (tid < 32) mval = (float)mask[(size_t)b * Sn + s0 + tid];

    // ---- K-loop on current chunk (4 MFMA / K-step / wave) ----
    f32x4 acc[2][2];
#pragma unroll
    for (int p = 0; p < 2; ++p)
#pragma unroll
      for (int q = 0; q < 2; ++q) acc[p][q] = (f32x4){0.f, 0.f, 0.f, 0.f};

#pragma unroll 4
    for (int kk = 0; kk < NK; ++kk) {
      const char* wk = wlane + (size_t)kk * 16384;
      bf16x8 bfr0 = *(const bf16x8*)(wk);
      bf16x8 bfr1 = *(const bf16x8*)(wk + 1024);
      bf16x8 a0 = *(const bf16x8*)(cbuf + (((arow     ) * 1536 + kk * 64 + akoff) ^ swz));
      bf16x8 a1 = *(const bf16x8*)(cbuf + (((arow + 16) * 1536 + kk * 64 + akoff) ^ swz));
      acc[0][0] = __builtin_amdgcn_mfma_f32_16x16x32_bf16(a0, bfr0, acc[0][0], 0, 0, 0);
      acc[1][0] = __builtin_amdgcn_mfma_f32_16x16x32_bf16(a1, bfr0, acc[1][0], 0, 0, 0);
      acc[0][1] = __builtin_amdgcn_mfma_f32_16x16x32_bf16(a0, bfr1, acc[0][1], 0, 0, 0);
      acc[1][1] = __builtin_amdgcn_mfma_f32_16x16x32_bf16(a1, bfr1, acc[1][1], 0, 0, 0);
    }

    // ---- cvt chunk i+1 regs -> other buffer, then issue chunk i+2 ----
    if (i + 1 < CPB) {
      char* nbuf = xs[(i + 1) & 1];
#pragma unroll
      for (int j = 0; j < 6; ++j) {
        int unit = tid + j * 512;
        int row = unit / 96, ku = unit % 96;
        bf16x8 pk;
        pk[0] = (__bf16)ld0[j].x; pk[1] = (__bf16)ld0[j].y;
        pk[2] = (__bf16)ld0[j].z; pk[3] = (__bf16)ld0[j].w;
        pk[4] = (__bf16)ld1[j].x; pk[5] = (__bf16)ld1[j].y;
        pk[6] = (__bf16)ld1[j].z; pk[7] = (__bf16)ld1[j].w;
        int off = (row * 1536 + ku * 16) ^ ((row & 7) << 4);
        *(bf16x8*)(nbuf + off) = pk;
      }
      if (i + 2 < CPB) {
        const int nc = cid + 2;
        const float* xb = x + ((size_t)b * Sn + (size_t)(nc & 63) * ROWS) * Dn;
#pragma unroll
        for (int j = 0; j < 6; ++j) {
          int unit = tid + j * 512;
          int row = unit / 96, ku = unit % 96;
          const float4* g = (const float4*)(xb + row * Dn + ku * 8);
          ld0[j] = g[0];
          ld1[j] = g[1];
        }
        asm volatile("" ::: "memory");   // pin issue; epilogue/pool overlap the stream
      }
    }

    // ---- epilogue: tanh + dot with u -> per-row partials (wave covers 32 cols) ----
    float rowp[8];
#pragma unroll
    for (int p = 0; p < 8; ++p) rowp[p] = 0.f;
#pragma unroll
    for (int cbi = 0; cbi < 2; ++cbi) {
      int col = wv * 32 + cbi * 16 + arow;
      float bia = bias[col];
      float uv  = u[col];
#pragma unroll
      for (int rb = 0; rb < 2; ++rb) {
#pragma unroll
        for (int r = 0; r < 4; ++r) {
          float v = acc[rb][cbi][r] + bia;
          v = fminf(fmaxf(v, -15.f), 15.f);
          float e2 = __expf(2.f * v);
          float th = (e2 - 1.f) * __builtin_amdgcn_rcpf(e2 + 1.f);
          rowp[rb * 4 + r] += th * uv;
        }
      }
    }
#pragma unroll
    for (int m = 1; m < 16; m <<= 1)
#pragma unroll
      for (int p = 0; p < 8; ++p) rowp[p] += __shfl_xor(rowp[p], m, 64);

    if (arow == 0) {
      int rbase = (lane >> 4) * 4;
#pragma unroll
      for (int rb = 0; rb < 2; ++rb)
#pragma unroll
        for (int r = 0; r < 4; ++r)
          aitp[wv * 32 + rb * 16 + rbase + r] = rowp[rb * 4 + r];
    }
    asm volatile("s_waitcnt lgkmcnt(0)" ::: "memory");
    __builtin_amdgcn_s_barrier();   // S1: aitp ready; nbuf published

    if (tid < 32) {
      float s = 0.f;
#pragma unroll
      for (int k = 0; k < 8; ++k) s += aitp[k * 32 + tid];
      float av = __expf(s) * mval;
      aitv[tid] = av;
      float t = av;
#pragma unroll
      for (int m = 1; m < 32; m <<= 1) t += __shfl_xor(t, m, 64);
      if (tid == 0) sumpart[cid] = t;
    }
    asm volatile("s_waitcnt lgkmcnt(0)" ::: "memory");
    __builtin_amdgcn_s_barrier();   // S2: aitv ready

    // ---- pooling: 384 threads, 4 row-groups of 8 rows ----
    if (tid < 384) {
      int rg = tid / 96;            // 0..3
      int du = tid % 96;            // 8-d unit
      float pac[8];
#pragma unroll
      for (int e = 0; e < 8; ++e) pac[e] = 0.f;
#pragma unroll
      for (int rr = 0; rr < 8; ++rr) {
        int row = rg * 8 + rr;
        int off = (row * 1536 + du * 16) ^ ((row & 7) << 4);
        bf16x8 xv = *(const bf16x8*)(cbuf + off);
        float a = aitv[row];
#pragma unroll
        for (int e = 0; e < 8; ++e) pac[e] += a * (float)xv[e];
      }
#pragma unroll
      for (int e = 0; e < 8; ++e) outred[rg * 768 + du * 8 + e] = pac[e];
    }
    asm volatile("s_waitcnt lgkmcnt(0)" ::: "memory");
    __builtin_amdgcn_s_barrier();   // S3: outred ready; cbuf reads done

    if (tid < 256) {
      float* op = outpart + (size_t)cid * Dn;
#pragma unroll
      for (int j = 0; j < 3; ++j) {
        int d = tid + j * 256;
        op[d] = outred[d] + outred[768 + d] + outred[1536 + d] + outred[2304 + d];
      }
    }
    __builtin_amdgcn_s_barrier();   // S4: outred/buf reuse fence for next iter
  }
}

// ---------------- finalize: out[b,d] = sum_c outpart / (sum_c sumpart + eps) ----
// grid = 64 b x 3 slabs of 256 d
__global__ void finalize_kernel(const float* __restrict__ outpart,
                                const float* __restrict__ sumpart,
                                float* __restrict__ out) {
  __shared__ float sh;
  int b = blockIdx.x / 3, slab = blockIdx.x % 3;
  int tid = threadIdx.x;
  if (tid < 64) {
    float v = sumpart[b * 64 + tid];
#pragma unroll
    for (int m = 1; m < 64; m <<= 1) v += __shfl_xor(v, m, 64);
    if (tid == 0) sh = v + EPSF;
  }
  __syncthreads();
  float inv = 1.0f / sh;
  int d = slab * 256 + tid;
  const float* p = outpart + (size_t)b * 64 * Dn + d;
  float s = 0.f;
#pragma unroll 8
  for (int c = 0; c < 64; ++c) s += p[(size_t)c * Dn];
  out[b * Dn + d] = s * inv;
}

extern "C" void kernel_launch(void* const* d_in, const int* in_sizes, int n_in,
                              void* d_out, int out_size, void* d_ws, size_t ws_size,
                              hipStream_t stream) {
  const float* x    = (const float*)d_in[0];
  const float* W    = (const float*)d_in[1];
  const float* bias = (const float*)d_in[2];
  const float* u    = (const float*)d_in[3];
  const int*   mask = (const int*)d_in[4];
  float* out = (float*)d_out;

  unsigned short* pw = (unsigned short*)d_ws;                      // 393216 B
  float* outpart = (float*)((char*)d_ws + 393216);                 // 64*64*768*4 = 12.58 MB
  float* sumpart = (float*)((char*)d_ws + 393216 + 12582912);      // 16 KB

  hipLaunchKernelGGL(pack_w_kernel, dim3(24 * 16), dim3(64), 0, stream, W, pw);
  hipLaunchKernelGGL(attn_pool_main, dim3(NBLK), dim3(512), 0, stream,
                     x, pw, bias, u, mask, outpart, sumpart);
  hipLaunchKernelGGL(finalize_kernel, dim3(Bn * 3), dim3(256), 0, stream,
                     outpart, sumpart, out);
}